// Round 7
// baseline (243.212 us; speedup 1.0000x reference)
//
#include <hip/hip_runtime.h>

// PointNetSaModule fused — f32 in/out, f16 MFMA compute.
// R13: all-weights-in-registers. Six-round model: pipe-busy %s only reconcile
// at reduced effective clock -> kernel is ISSUE-saturated (VALU+DS dominate);
// latency/occupancy/BW levers all proved <=0 (R10/R11/R12). Biggest removable
// issue slice = per-iter weight/bias LDS reads (24 b128 + t1/t2 per wave-iter).
//   - W1 frags (32 VGPR) + W2 frags (64) + b0f (48) + t1 (16) + t2 (8) = 168
//     persistent regs; hoisted ONCE at setup via the validated LDS fold.
//   - launch_bounds(256,2) -> 256-VGPR cap, est demand ~230. Spill canary:
//     FETCH_SIZE (R7 lesson). Fallback: W2 back to LDS.
//   - 1 pt/wave (R11-validated body; weight amortization now moot), grid 512
//     = 2 blocks/CU, 32 iters exact. nidx depth-1 prefetch only (R12: data
//     prefetch defeated + rotation VALU hurt; XCD affinity FETCH↓ but time↑).
//   - cvt_pkrtz packs relu'd f32 pair -> f16x2 in 1 inst (RTZ; <=1 ulp vs RTE,
//     threshold headroom 4x).
// LDS: only X' u32-pair transpose (R10-validated, stride 36) + setup fold
// buffers. Main-loop DS = 8 b64 writes + 4 b128 reads + 16 shfl per point.

#define NGRP_    16384        // groups of 4 points (1 per wave)
#define OUTHALF_ 8388608      // elements: second output copy offset
#define WS_      72           // padded f16 stride of W1'/W2' fold rows
#define XS2_     36           // u32 stride of X' rows (144B, 16B-multiple)
#define EPS_     1e-5f
#define GRID_    512          // 2 blocks/CU x 256 CUs, 32 iters exact

typedef _Float16 h8    __attribute__((ext_vector_type(8)));
typedef _Float16 h2    __attribute__((ext_vector_type(2)));
typedef float    f32x4 __attribute__((ext_vector_type(4)));
typedef unsigned u32x2 __attribute__((ext_vector_type(2)));

__global__ __launch_bounds__(256) void cvt_pts_kernel(
    const float* __restrict__ src, _Float16* __restrict__ dst)
{
    const size_t i = ((size_t)blockIdx.x * 256 + threadIdx.x) * 8;
    f32x4 a = *(const f32x4*)(src + i);
    f32x4 b = *(const f32x4*)(src + i + 4);
    h8 o;
#pragma unroll
    for (int j = 0; j < 4; ++j) { o[j] = (_Float16)a[j]; o[4 + j] = (_Float16)b[j]; }
    *(h8*)(dst + i) = o;
}

// relu + pack two f32 -> one u32 of 2 f16, single v_cvt_pkrtz_f16_f32
#define PK2(lo, hi) __builtin_bit_cast(unsigned,                               \
    __builtin_amdgcn_cvt_pkrtz(fmaxf((lo), 0.f), fmaxf((hi), 0.f)))

template<bool PRE>   // PRE: pts pre-converted to f16 in workspace
__global__ __launch_bounds__(256, 2) void pnsa_main(
    const float* __restrict__ xyz,    // (B,HW,3) f32
    const void*  __restrict__ ptsv,   // f16 ws if PRE, else f32 (B,HW,64)
    const float* __restrict__ xyzs,   // (B,NPT,3) f32
    const int*   __restrict__ nidx,   // (B,NPT*16)
    const float* __restrict__ vmask,  // (B,NPT,16) f32
    const float* __restrict__ w0, const float* __restrict__ b0,
    const float* __restrict__ g0, const float* __restrict__ be0,
    const float* __restrict__ m0, const float* __restrict__ v0,
    const float* __restrict__ w1, const float* __restrict__ b1,
    const float* __restrict__ g1, const float* __restrict__ be1,
    const float* __restrict__ m1, const float* __restrict__ v1,
    const float* __restrict__ w2, const float* __restrict__ b2,
    const float* __restrict__ g2, const float* __restrict__ be2,
    const float* __restrict__ m2, const float* __restrict__ v2,
    float*       __restrict__ out)
{
    __shared__ __align__(16) _Float16 ldsW1[64 * WS_];        // fold buf  9216B
    __shared__ __align__(16) _Float16 ldsW2[128 * WS_];       // fold buf 18432B
    __shared__ __align__(16) float    s1sh[64], t1sh[64];     //            512B
    __shared__ __align__(16) float    s2sh[128], t2sh[128];   //           1024B
    __shared__ __align__(16) unsigned ldsX[4][16 * XS2_];     // X' u32    9216B
    // total 38,400B; occupancy bound by VGPR (2 waves/SIMD), not LDS

    const int tid  = threadIdx.x;
    const int wave = tid >> 6;
    const int lane = tid & 63;
    const int l15  = lane & 15;
    const int quad = lane >> 4;

    unsigned* Xp = &ldsX[wave][0];

    // ---- stage BN scales + shifted biases ----
    if (tid < 64) {
        const float s = g1[tid] * rsqrtf(v1[tid] + EPS_);
        s1sh[tid] = s;
        t1sh[tid] = (b1[tid] - m1[tid]) * s + be1[tid];
    }
    if (tid < 128) {
        const float s = g2[tid] * rsqrtf(v2[tid] + EPS_);
        s2sh[tid] = s;
        t2sh[tid] = (b2[tid] - m2[tid]) * s + be2[tid];
    }
    __syncthreads();
    // ---- fold W1'/W2' into LDS (validated path), then hoist frags to regs ----
    for (int idx = tid; idx < 64 * 64; idx += 256) {     // w1[k][n] -> W1'[n][k]
        const int k = idx >> 6, n = idx & 63;
        ldsW1[n * WS_ + k] = (_Float16)(w1[idx] * s1sh[n]);
    }
    for (int idx = tid; idx < 64 * 128; idx += 256) {    // w2[k][n] -> W2'[n][k]
        const int k = idx >> 7, n = idx & 127;
        ldsW2[n * WS_ + k] = (_Float16)(w2[idx] * s2sh[n]);
    }
    __syncthreads();

    // W1/W2 fragments -> registers (persistent; statically indexed only)
    h8 w1f[4][2], w2f[8][2];
#pragma unroll
    for (int nt = 0; nt < 4; ++nt) {
        const _Float16* wrow = ldsW1 + (nt * 16 + l15) * WS_ + quad * 8;
        w1f[nt][0] = *(const h8*)(wrow);
        w1f[nt][1] = *(const h8*)(wrow + 32);
    }
#pragma unroll
    for (int nt = 0; nt < 8; ++nt) {
        const _Float16* wrow = ldsW2 + (nt * 16 + l15) * WS_ + quad * 8;
        w2f[nt][0] = *(const h8*)(wrow);
        w2f[nt][1] = *(const h8*)(wrow + 32);
    }
    // biases -> registers
    f32x4 t1v[4];
#pragma unroll
    for (int nt = 0; nt < 4; ++nt)
        t1v[nt] = *(const f32x4*)(t1sh + nt * 16 + quad * 4);
    float t2v[8];
#pragma unroll
    for (int nt = 0; nt < 8; ++nt) t2v[nt] = t2sh[nt * 16 + l15];

    // ---- W0 BN-folded into register frags; bias via pad channel 67 ----
    // Feature k-order: [points 0..63, xyz_diff 64..66, BIAS 67 (=1.0), pad..95]
    // Frag map (A==B on gfx950): lane holds [ch=nt*16+l15][k=kk*32+quad*8+j]
    h8 b0f[4][3];
#pragma unroll
    for (int nt = 0; nt < 4; ++nt) {
        const int ch = nt * 16 + l15;
        const float s = g0[ch] * rsqrtf(v0[ch] + EPS_);
        const float t0 = (b0[ch] - m0[ch]) * s + be0[ch];
#pragma unroll
        for (int kk = 0; kk < 3; ++kk) {
            h8 f;
#pragma unroll
            for (int j = 0; j < 8; ++j) {
                const int k = kk * 32 + quad * 8 + j;
                float wv = 0.f;
                if (k < 64)       wv = w0[(3 + k) * 64 + ch] * s;
                else if (k < 67)  wv = w0[(k - 64) * 64 + ch] * s;
                else if (k == 67) wv = t0;                 // bias via 1.0 channel
                f[j] = (_Float16)wv;
            }
            b0f[nt][kk] = f;
        }
    }

    // ---- main loop: 4 points per block iteration (1 per wave) ----
    int nb = nidx[((((blockIdx.x) << 2) + wave) << 4) + l15];   // depth-1 nidx

    for (int grp = blockIdx.x; grp < NGRP_; grp += GRID_) {
        const int p = (grp << 2) + wave;
        const int gn = (grp + GRID_ < NGRP_) ? grp + GRID_ : grp;
        const int pn = (gn << 2) + wave;

        // gather current point (issue early), prefetch next nidx
        const size_t row = (size_t)(((p >> 14) << 16) + nb);
        h8 q0, q1;
        if constexpr (PRE) {
            const _Float16* pw = (const _Float16*)ptsv + (row << 6);
            q0 = *(const h8*)(pw + quad * 8);
            q1 = *(const h8*)(pw + 32 + quad * 8);
        } else {
            const float* pw = (const float*)ptsv + (row << 6);
            f32x4 r0 = *(const f32x4*)(pw + quad * 8);
            f32x4 r1 = *(const f32x4*)(pw + quad * 8 + 4);
            f32x4 r2 = *(const f32x4*)(pw + 32 + quad * 8);
            f32x4 r3 = *(const f32x4*)(pw + 32 + quad * 8 + 4);
#pragma unroll
            for (int j = 0; j < 4; ++j) { q0[j]=(_Float16)r0[j]; q0[4+j]=(_Float16)r1[j];
                                          q1[j]=(_Float16)r2[j]; q1[4+j]=(_Float16)r3[j]; }
        }
        const float mk = vmask[(p << 4) + l15];
        const float* xgp = xyz + row * 3;
        const float xg0 = xgp[0], xg1 = xgp[1], xg2 = xgp[2];
        const float* xsp = xyzs + (size_t)p * 3;
        const float xs0 = xsp[0], xs1 = xsp[1], xs2 = xsp[2];
        const int nb_n = nidx[(pn << 4) + l15];

        if (mk == 0.0f) { q0 = (h8)(_Float16)0.f; q1 = (h8)(_Float16)0.f; }
        h8 a2 = (h8)(_Float16)0.f;
        if (quad == 0) {
            a2[0] = (_Float16)(xg0 * mk - xs0);
            a2[1] = (_Float16)(xg1 * mk - xs1);
            a2[2] = (_Float16)(xg2 * mk - xs2);
            a2[3] = (_Float16)1.0f;               // bias channel
        }

        // ---- layer 0 SWAPPED: D = W0'' X^T -> acc[r] = X1[16nt+4q+r][nb=l15]
#pragma unroll
        for (int nt = 0; nt < 4; ++nt) {
            f32x4 acc = {0.f, 0.f, 0.f, 0.f};
            acc = __builtin_amdgcn_mfma_f32_16x16x32_f16(b0f[nt][0], q0, acc, 0, 0, 0);
            acc = __builtin_amdgcn_mfma_f32_16x16x32_f16(b0f[nt][1], q1, acc, 0, 0, 0);
            acc = __builtin_amdgcn_mfma_f32_16x16x32_f16(b0f[nt][2], a2, acc, 0, 0, 0);
            u32x2 pk = {PK2(acc[0], acc[1]), PK2(acc[2], acc[3])};
            *(u32x2*)(Xp + l15 * XS2_ + nt * 8 + quad * 2) = pk;
        }

        // ---- layer 1 SWAPPED (reads precede overwrites; DS in-order/wave) ----
        h8 x0 = *(const h8*)(Xp + l15 * XS2_ + quad * 4);
        h8 x1 = *(const h8*)(Xp + l15 * XS2_ + 16 + quad * 4);
#pragma unroll
        for (int nt = 0; nt < 4; ++nt) {
            f32x4 acc = t1v[nt];         // bias in accumulator (ch = 16nt+4q+r)
            acc = __builtin_amdgcn_mfma_f32_16x16x32_f16(w1f[nt][0], x0, acc, 0, 0, 0);
            acc = __builtin_amdgcn_mfma_f32_16x16x32_f16(w1f[nt][1], x1, acc, 0, 0, 0);
            u32x2 pk = {PK2(acc[0], acc[1]), PK2(acc[2], acc[3])};
            *(u32x2*)(Xp + l15 * XS2_ + nt * 8 + quad * 2) = pk;
        }

        // ---- layer 2 NORMAL: A-operand from X' + K-maxpool + stores ----
        h8 y0 = *(const h8*)(Xp + l15 * XS2_ + quad * 4);
        h8 y1 = *(const h8*)(Xp + l15 * XS2_ + 16 + quad * 4);
        float* ob = out + ((size_t)p << 7);
#pragma unroll
        for (int nt = 0; nt < 8; ++nt) {
            f32x4 acc = {0.f, 0.f, 0.f, 0.f};
            acc = __builtin_amdgcn_mfma_f32_16x16x32_f16(y0, w2f[nt][0], acc, 0, 0, 0);
            acc = __builtin_amdgcn_mfma_f32_16x16x32_f16(y1, w2f[nt][1], acc, 0, 0, 0);
            float v = fmaxf(fmaxf(acc[0], acc[1]), fmaxf(acc[2], acc[3])) + t2v[nt];
            v = fmaxf(v, 0.f);                        // relu(max)=max(relu)
            v = fmaxf(v, __shfl_xor(v, 16, 64));
            v = fmaxf(v, __shfl_xor(v, 32, 64));
            if (quad == 0) {
                ob[nt * 16 + l15]            = v;
                ob[OUTHALF_ + nt * 16 + l15] = v;
            }
        }

        nb = nb_n;
    }
}

extern "C" void kernel_launch(void* const* d_in, const int* in_sizes, int n_in,
                              void* d_out, int out_size, void* d_ws, size_t ws_size,
                              hipStream_t stream) {
    const float* xyz   = (const float*)d_in[0];
    const float* pts   = (const float*)d_in[1];
    const float* xyzs  = (const float*)d_in[2];
    const int*   nidx  = (const int*)d_in[3];
    const float* vmask = (const float*)d_in[4];
    const float *w0 = (const float*)d_in[5],  *b0 = (const float*)d_in[6],
                *g0 = (const float*)d_in[7],  *be0 = (const float*)d_in[8],
                *m0 = (const float*)d_in[9],  *v0 = (const float*)d_in[10];
    const float *w1 = (const float*)d_in[11], *b1 = (const float*)d_in[12],
                *g1 = (const float*)d_in[13], *be1 = (const float*)d_in[14],
                *m1 = (const float*)d_in[15], *v1 = (const float*)d_in[16];
    const float *w2 = (const float*)d_in[17], *b2 = (const float*)d_in[18],
                *g2 = (const float*)d_in[19], *be2 = (const float*)d_in[20],
                *m2 = (const float*)d_in[21], *v2 = (const float*)d_in[22];
    float* outp = (float*)d_out;

    const size_t PTS_ELEMS = 16777216ull;           // 4*65536*64
    if (ws_size >= PTS_ELEMS * sizeof(_Float16)) {
        _Float16* ptsh = (_Float16*)d_ws;
        cvt_pts_kernel<<<dim3(8192), dim3(256), 0, stream>>>(pts, ptsh);
        pnsa_main<true><<<dim3(GRID_), dim3(256), 0, stream>>>(
            xyz, (const void*)ptsh, xyzs, nidx, vmask,
            w0, b0, g0, be0, m0, v0,
            w1, b1, g1, be1, m1, v1,
            w2, b2, g2, be2, m2, v2, outp);
    } else {
        pnsa_main<false><<<dim3(GRID_), dim3(256), 0, stream>>>(
            xyz, (const void*)pts, xyzs, nidx, vmask,
            w0, b0, g0, be0, m0, v0,
            w1, b1, g1, be1, m1, v1,
            w2, b2, g2, be2, m2, v2, outp);
    }
}

// Round 8
// 212.873 us; speedup vs baseline: 1.1425x; 1.1425x over previous
//
#include <hip/hip_runtime.h>

// PointNetSaModule fused — f32 in/out, f16 MFMA compute.
// R14 = R10 base (best verified main kernel: 84.5us, 2pt/wave, swapped L0/L1,
// u32-pair LDS transpose, (256,3)/768) + headline attack:
//   (a) DROP cvt_pts pre-pass: gather pts as f32 directly (PRE=false path).
//       f16 path HBM/launch = 100MB (cvt) + 77MB (main) = 177MB; f32 path
//       ~95MB (67MB pts read once, L3 absorbs random re-reads). R12 proved
//       the main kernel is NOT gather-BW-bound, so halving gather bytes never
//       paid for the extra dispatch. Saves ~45us HBM time + 1 launch.
//   (b) packed output stores: post-reduce value is quad-uniform -> cndmask
//       chain selects channel per lane; ALL 64 lanes store. 8 coalesced 256B
//       stores per wave-iter vs 32 exec-masked 64B stores.
// R13 post-mortem: weights-in-regs never executed (VGPR=124 -> compiler sank
// frag reads back to LDS; occupancy 20%); theory untested, config worse.

#define NGRP_    8192         // groups of 8 points (B*h*w/8)
#define OUTHALF_ 8388608      // elements: second output copy offset
#define WS_      72           // padded f16 stride of W1'/W2' rows (need 64)
#define XS2_     36           // u32 stride of X' rows (need 32; 144B, 16B-mult)
#define EPS_     1e-5f
#define GRID_    768          // 3 blocks/CU x 256 CUs

typedef _Float16 h8    __attribute__((ext_vector_type(8)));
typedef float    f32x4 __attribute__((ext_vector_type(4)));
typedef unsigned u32x2 __attribute__((ext_vector_type(2)));

// relu + cvt + pack two f32 into one u32 of 2 f16 (RTE casts, R6/R10 numerics)
#define PK(lo, hi) ({                                                          \
    const _Float16 _l = (_Float16)fmaxf((lo), 0.f);                            \
    const _Float16 _h = (_Float16)fmaxf((hi), 0.f);                            \
    (unsigned)__builtin_bit_cast(unsigned short, _l) |                         \
    ((unsigned)__builtin_bit_cast(unsigned short, _h) << 16); })

__global__ __launch_bounds__(256, 3) void pnsa_main(
    const float* __restrict__ xyz,    // (B,HW,3) f32
    const float* __restrict__ pts,    // (B,HW,64) f32
    const float* __restrict__ xyzs,   // (B,NPT,3) f32
    const int*   __restrict__ nidx,   // (B,NPT*16)
    const float* __restrict__ vmask,  // (B,NPT,16) f32
    const float* __restrict__ w0, const float* __restrict__ b0,
    const float* __restrict__ g0, const float* __restrict__ be0,
    const float* __restrict__ m0, const float* __restrict__ v0,
    const float* __restrict__ w1, const float* __restrict__ b1,
    const float* __restrict__ g1, const float* __restrict__ be1,
    const float* __restrict__ m1, const float* __restrict__ v1,
    const float* __restrict__ w2, const float* __restrict__ b2,
    const float* __restrict__ g2, const float* __restrict__ be2,
    const float* __restrict__ m2, const float* __restrict__ v2,
    float*       __restrict__ out)
{
    __shared__ __align__(16) _Float16 ldsW1[64 * WS_];        // W1'[n][k]  9216B
    __shared__ __align__(16) _Float16 ldsW2[128 * WS_];       // W2'[n][k] 18432B
    __shared__ __align__(16) float    s1sh[64], t1sh[64];     //             512B
    __shared__ __align__(16) float    s2sh[128], t2sh[128];   //            1024B
    __shared__ __align__(16) unsigned ldsX[4][2][16 * XS2_];  // X' u32   18432B

    const int tid  = threadIdx.x;
    const int wave = tid >> 6;
    const int lane = tid & 63;
    const int l15  = lane & 15;
    const int quad = lane >> 4;

    unsigned* XA = &ldsX[wave][0][0];
    unsigned* XB = &ldsX[wave][1][0];

    // ---- stage BN scales + shifted biases, then W1'/W2' folded into LDS ----
    if (tid < 64) {
        const float s = g1[tid] * rsqrtf(v1[tid] + EPS_);
        s1sh[tid] = s;
        t1sh[tid] = (b1[tid] - m1[tid]) * s + be1[tid];
    }
    if (tid < 128) {
        const float s = g2[tid] * rsqrtf(v2[tid] + EPS_);
        s2sh[tid] = s;
        t2sh[tid] = (b2[tid] - m2[tid]) * s + be2[tid];
    }
    __syncthreads();
    for (int idx = tid; idx < 64 * 64; idx += 256) {     // w1[k][n] -> W1'[n][k]
        const int k = idx >> 6, n = idx & 63;
        ldsW1[n * WS_ + k] = (_Float16)(w1[idx] * s1sh[n]);
    }
    for (int idx = tid; idx < 64 * 128; idx += 256) {    // w2[k][n] -> W2'[n][k]
        const int k = idx >> 7, n = idx & 127;
        ldsW2[n * WS_ + k] = (_Float16)(w2[idx] * s2sh[n]);
    }
    __syncthreads();

    // ---- W0 BN-folded into register frags; bias via pad channel 67 ----
    // Feature k-order: [points 0..63, xyz_diff 64..66, BIAS 67 (=1.0), pad..95]
    // Frag map (A==B on gfx950): lane holds [ch=nt*16+l15][k=kk*32+quad*8+j]
    h8 b0f[4][3];
#pragma unroll
    for (int nt = 0; nt < 4; ++nt) {
        const int ch = nt * 16 + l15;
        const float s = g0[ch] * rsqrtf(v0[ch] + EPS_);
        const float t0 = (b0[ch] - m0[ch]) * s + be0[ch];
#pragma unroll
        for (int kk = 0; kk < 3; ++kk) {
            h8 f;
#pragma unroll
            for (int j = 0; j < 8; ++j) {
                const int k = kk * 32 + quad * 8 + j;
                float wv = 0.f;
                if (k < 64)       wv = w0[(3 + k) * 64 + ch] * s;
                else if (k < 67)  wv = w0[(k - 64) * 64 + ch] * s;
                else if (k == 67) wv = t0;                 // bias via 1.0 channel
                f[j] = (_Float16)wv;
            }
            b0f[nt][kk] = f;
        }
    }

    // ---- main loop: 8 points per block iteration (2 per wave) ----
    const int g0i = blockIdx.x;
    const int pA0 = (g0i << 3) + (wave << 1);
    int nbA = nidx[(pA0 << 4) + l15];
    int nbB = nidx[((pA0 + 1) << 4) + l15];

    for (int grp = g0i; grp < NGRP_; grp += GRID_) {
        const int pA = (grp << 3) + (wave << 1);
        const int pB = pA + 1;
        const int gn = (grp + GRID_ < NGRP_) ? grp + GRID_ : grp;
        const int pAn = (gn << 3) + (wave << 1);

        // gather loads for both points (issue early), f32 direct
        const size_t rowA = (size_t)(((pA >> 14) << 16) + nbA);
        const size_t rowB = (size_t)(((pB >> 14) << 16) + nbB);
        h8 qA0, qA1, qB0, qB1;
        {
            const float* pwA = pts + (rowA << 6);
            const float* pwB = pts + (rowB << 6);
            f32x4 r0, r1, r2, r3;
            r0 = *(const f32x4*)(pwA + quad * 8);      r1 = *(const f32x4*)(pwA + quad * 8 + 4);
            r2 = *(const f32x4*)(pwA + 32 + quad * 8); r3 = *(const f32x4*)(pwA + 32 + quad * 8 + 4);
#pragma unroll
            for (int j = 0; j < 4; ++j) { qA0[j]=(_Float16)r0[j]; qA0[4+j]=(_Float16)r1[j];
                                          qA1[j]=(_Float16)r2[j]; qA1[4+j]=(_Float16)r3[j]; }
            r0 = *(const f32x4*)(pwB + quad * 8);      r1 = *(const f32x4*)(pwB + quad * 8 + 4);
            r2 = *(const f32x4*)(pwB + 32 + quad * 8); r3 = *(const f32x4*)(pwB + 32 + quad * 8 + 4);
#pragma unroll
            for (int j = 0; j < 4; ++j) { qB0[j]=(_Float16)r0[j]; qB0[4+j]=(_Float16)r1[j];
                                          qB1[j]=(_Float16)r2[j]; qB1[4+j]=(_Float16)r3[j]; }
        }
        const float mkA = vmask[(pA << 4) + l15];
        const float mkB = vmask[(pB << 4) + l15];
        const float* xgA = xyz + rowA * 3;
        const float* xgB = xyz + rowB * 3;
        const float xgA0 = xgA[0], xgA1 = xgA[1], xgA2 = xgA[2];
        const float xgB0 = xgB[0], xgB1 = xgB[1], xgB2 = xgB[2];
        const float* xsA = xyzs + (size_t)pA * 3;
        const float* xsB = xyzs + (size_t)pB * 3;
        const float xsA0 = xsA[0], xsA1 = xsA[1], xsA2 = xsA[2];
        const float xsB0 = xsB[0], xsB1 = xsB[1], xsB2 = xsB[2];

        // prefetch next iteration's neighbor indices
        const int nbAn = nidx[(pAn << 4) + l15];
        const int nbBn = nidx[((pAn + 1) << 4) + l15];

        if (mkA == 0.0f) { qA0 = (h8)(_Float16)0.f; qA1 = (h8)(_Float16)0.f; }
        if (mkB == 0.0f) { qB0 = (h8)(_Float16)0.f; qB1 = (h8)(_Float16)0.f; }
        h8 aA2 = (h8)(_Float16)0.f, aB2 = (h8)(_Float16)0.f;
        if (quad == 0) {
            aA2[0] = (_Float16)(xgA0 * mkA - xsA0);
            aA2[1] = (_Float16)(xgA1 * mkA - xsA1);
            aA2[2] = (_Float16)(xgA2 * mkA - xsA2);
            aA2[3] = (_Float16)1.0f;               // bias channel
            aB2[0] = (_Float16)(xgB0 * mkB - xsB0);
            aB2[1] = (_Float16)(xgB1 * mkB - xsB1);
            aB2[2] = (_Float16)(xgB2 * mkB - xsB2);
            aB2[3] = (_Float16)1.0f;
        }

        // ---- layer 0 SWAPPED: D = W0'' X^T -> acc[r] = X1[16nt+4q+r][nb=l15]
#pragma unroll
        for (int nt = 0; nt < 4; ++nt) {
            f32x4 aA = {0.f,0.f,0.f,0.f}, aB = {0.f,0.f,0.f,0.f};
            aA = __builtin_amdgcn_mfma_f32_16x16x32_f16(b0f[nt][0], qA0, aA, 0, 0, 0);
            aA = __builtin_amdgcn_mfma_f32_16x16x32_f16(b0f[nt][1], qA1, aA, 0, 0, 0);
            aA = __builtin_amdgcn_mfma_f32_16x16x32_f16(b0f[nt][2], aA2, aA, 0, 0, 0);
            aB = __builtin_amdgcn_mfma_f32_16x16x32_f16(b0f[nt][0], qB0, aB, 0, 0, 0);
            aB = __builtin_amdgcn_mfma_f32_16x16x32_f16(b0f[nt][1], qB1, aB, 0, 0, 0);
            aB = __builtin_amdgcn_mfma_f32_16x16x32_f16(b0f[nt][2], aB2, aB, 0, 0, 0);
            u32x2 pkA = {PK(aA[0], aA[1]), PK(aA[2], aA[3])};
            u32x2 pkB = {PK(aB[0], aB[1]), PK(aB[2], aB[3])};
            *(u32x2*)(XA + l15 * XS2_ + nt * 8 + quad * 2) = pkA;
            *(u32x2*)(XB + l15 * XS2_ + nt * 8 + quad * 2) = pkB;
        }

        // ---- layer 1 SWAPPED (reads precede overwrites; DS in-order/wave) ----
        h8 xA0 = *(const h8*)(XA + l15 * XS2_ + quad * 4);
        h8 xA1 = *(const h8*)(XA + l15 * XS2_ + 16 + quad * 4);
        h8 xB0 = *(const h8*)(XB + l15 * XS2_ + quad * 4);
        h8 xB1 = *(const h8*)(XB + l15 * XS2_ + 16 + quad * 4);
#pragma unroll 2
        for (int nt = 0; nt < 4; ++nt) {
            const _Float16* wrow = ldsW1 + (nt * 16 + l15) * WS_ + quad * 8;
            h8 wa = *(const h8*)(wrow);
            h8 wb = *(const h8*)(wrow + 32);
            const f32x4 t1 = *(const f32x4*)(t1sh + nt * 16 + quad * 4);
            f32x4 aA = t1, aB = t1;      // bias in accumulator (ch = 16nt+4q+r)
            aA = __builtin_amdgcn_mfma_f32_16x16x32_f16(wa, xA0, aA, 0, 0, 0);
            aA = __builtin_amdgcn_mfma_f32_16x16x32_f16(wb, xA1, aA, 0, 0, 0);
            aB = __builtin_amdgcn_mfma_f32_16x16x32_f16(wa, xB0, aB, 0, 0, 0);
            aB = __builtin_amdgcn_mfma_f32_16x16x32_f16(wb, xB1, aB, 0, 0, 0);
            u32x2 pkA = {PK(aA[0], aA[1]), PK(aA[2], aA[3])};
            u32x2 pkB = {PK(aB[0], aB[1]), PK(aB[2], aB[3])};
            *(u32x2*)(XA + l15 * XS2_ + nt * 8 + quad * 2) = pkA;
            *(u32x2*)(XB + l15 * XS2_ + nt * 8 + quad * 2) = pkB;
        }

        // ---- layer 2 NORMAL: X frags as A-operand + K-maxpool + packed stores
        h8 yA0 = *(const h8*)(XA + l15 * XS2_ + quad * 4);
        h8 yA1 = *(const h8*)(XA + l15 * XS2_ + 16 + quad * 4);
        h8 yB0 = *(const h8*)(XB + l15 * XS2_ + quad * 4);
        h8 yB1 = *(const h8*)(XB + l15 * XS2_ + 16 + quad * 4);
        float sAlo = 0.f, sAhi = 0.f, sBlo = 0.f, sBhi = 0.f;
#pragma unroll 2
        for (int nt = 0; nt < 8; ++nt) {
            const _Float16* wrow = ldsW2 + (nt * 16 + l15) * WS_ + quad * 8;
            h8 wa = *(const h8*)(wrow);
            h8 wb = *(const h8*)(wrow + 32);
            const float t2 = t2sh[nt * 16 + l15];
            f32x4 aA = {0.f,0.f,0.f,0.f}, aB = {0.f,0.f,0.f,0.f};
            aA = __builtin_amdgcn_mfma_f32_16x16x32_f16(yA0, wa, aA, 0, 0, 0);
            aA = __builtin_amdgcn_mfma_f32_16x16x32_f16(yA1, wb, aA, 0, 0, 0);
            aB = __builtin_amdgcn_mfma_f32_16x16x32_f16(yB0, wa, aB, 0, 0, 0);
            aB = __builtin_amdgcn_mfma_f32_16x16x32_f16(yB1, wb, aB, 0, 0, 0);
            float vA = fmaxf(fmaxf(aA[0], aA[1]), fmaxf(aA[2], aA[3])) + t2;
            float vB = fmaxf(fmaxf(aB[0], aB[1]), fmaxf(aB[2], aB[3])) + t2;
            vA = fmaxf(vA, 0.f);  vB = fmaxf(vB, 0.f);    // relu(max)=max(relu)
            vA = fmaxf(vA, __shfl_xor(vA, 16, 64));
            vA = fmaxf(vA, __shfl_xor(vA, 32, 64));       // now quad-uniform
            vB = fmaxf(vB, __shfl_xor(vB, 16, 64));
            vB = fmaxf(vB, __shfl_xor(vB, 32, 64));
            // select this lane's channel (ch = quad*16+l15 or +64):
            if (nt < 4) {
                sAlo = (quad == nt) ? vA : sAlo;
                sBlo = (quad == nt) ? vB : sBlo;
            } else {
                sAhi = (quad == nt - 4) ? vA : sAhi;
                sBhi = (quad == nt - 4) ? vB : sBhi;
            }
        }
        // all 64 lanes store; lane = quad*16+l15 -> 256B coalesced stores
        {
            float* obA = out + ((size_t)pA << 7);
            float* obB = out + ((size_t)pB << 7);
            obA[lane]                  = sAlo;
            obA[64 + lane]             = sAhi;
            obA[OUTHALF_ + lane]       = sAlo;
            obA[OUTHALF_ + 64 + lane]  = sAhi;
            obB[lane]                  = sBlo;
            obB[64 + lane]             = sBhi;
            obB[OUTHALF_ + lane]       = sBlo;
            obB[OUTHALF_ + 64 + lane]  = sBhi;
        }

        nbA = nbAn; nbB = nbBn;
    }
}

extern "C" void kernel_launch(void* const* d_in, const int* in_sizes, int n_in,
                              void* d_out, int out_size, void* d_ws, size_t ws_size,
                              hipStream_t stream) {
    const float* xyz   = (const float*)d_in[0];
    const float* pts   = (const float*)d_in[1];
    const float* xyzs  = (const float*)d_in[2];
    const int*   nidx  = (const int*)d_in[3];
    const float* vmask = (const float*)d_in[4];
    const float *w0 = (const float*)d_in[5],  *b0 = (const float*)d_in[6],
                *g0 = (const float*)d_in[7],  *be0 = (const float*)d_in[8],
                *m0 = (const float*)d_in[9],  *v0 = (const float*)d_in[10];
    const float *w1 = (const float*)d_in[11], *b1 = (const float*)d_in[12],
                *g1 = (const float*)d_in[13], *be1 = (const float*)d_in[14],
                *m1 = (const float*)d_in[15], *v1 = (const float*)d_in[16];
    const float *w2 = (const float*)d_in[17], *b2 = (const float*)d_in[18],
                *g2 = (const float*)d_in[19], *be2 = (const float*)d_in[20],
                *m2 = (const float*)d_in[21], *v2 = (const float*)d_in[22];
    float* outp = (float*)d_out;

    pnsa_main<<<dim3(GRID_), dim3(256), 0, stream>>>(
        xyz, pts, xyzs, nidx, vmask,
        w0, b0, g0, be0, m0, v0,
        w1, b1, g1, be1, m1, v1,
        w2, b2, g2, be2, m2, v2, outp);
}